// Round 1
// baseline (596.454 us; speedup 1.0000x reference)
//
#include <hip/hip_runtime.h>
#include <math.h>

// x: (B=64, C=128, T=10000) float32, contiguous, t fastest.
// Stage 1: m[b,t] = mean_c x[b,c,t]
// Stage 2: y = x - m;  per-(b,c): out = (y - mean_t y) / std_t y   (std==0 -> 1)

#define BB 64
#define CC 128
#define TT 10000
#define T4 2500   // TT/4

__global__ __launch_bounds__(256) void chmean_kernel(const float4* __restrict__ x,
                                                     float4* __restrict__ m) {
    const int t4 = blockIdx.x * 256 + threadIdx.x;
    const int b = blockIdx.y;
    if (t4 >= T4) return;
    const float4* xb = x + (size_t)b * CC * T4;
    float4 acc = make_float4(0.f, 0.f, 0.f, 0.f);
#pragma unroll 4
    for (int c = 0; c < CC; ++c) {
        float4 v = xb[(size_t)c * T4 + t4];
        acc.x += v.x; acc.y += v.y; acc.z += v.z; acc.w += v.w;
    }
    const float s = 1.0f / (float)CC;
    acc.x *= s; acc.y *= s; acc.z *= s; acc.w *= s;
    m[(size_t)b * T4 + t4] = acc;
}

__global__ __launch_bounds__(256) void zscore_kernel(const float4* __restrict__ x,
                                                     const float4* __restrict__ m,
                                                     float4* __restrict__ out) {
    __shared__ float4 y[T4];          // 40 KB: the referenced row, kept on-chip
    __shared__ float redS[4], redQ[4];
    __shared__ float s_mean, s_inv;

    const int tid = threadIdx.x;
    const int b = blockIdx.x >> 7;    // / 128
    const int c = blockIdx.x & 127;

    const float4* xr = x + ((size_t)b * CC + c) * T4;
    const float4* mr = m + (size_t)b * T4;

    float sum = 0.f, sq = 0.f;
    for (int i = tid; i < T4; i += 256) {
        float4 v = xr[i];
        float4 mv = mr[i];
        v.x -= mv.x; v.y -= mv.y; v.z -= mv.z; v.w -= mv.w;
        y[i] = v;
        sum += v.x + v.y + v.z + v.w;
        sq  += v.x * v.x + v.y * v.y + v.z * v.z + v.w * v.w;
    }

    // wave (64-lane) butterfly reduce
#pragma unroll
    for (int off = 32; off > 0; off >>= 1) {
        sum += __shfl_down(sum, off, 64);
        sq  += __shfl_down(sq,  off, 64);
    }
    const int wave = tid >> 6;
    if ((tid & 63) == 0) { redS[wave] = sum; redQ[wave] = sq; }
    __syncthreads();

    if (tid == 0) {
        const float S = redS[0] + redS[1] + redS[2] + redS[3];
        const float Q = redQ[0] + redQ[1] + redQ[2] + redQ[3];
        const float mean = S / (float)TT;
        float var = Q / (float)TT - mean * mean;
        if (var < 0.f) var = 0.f;
        const float sd = sqrtf(var);
        s_mean = mean;
        s_inv = (sd == 0.f) ? 1.f : 1.f / sd;
    }
    __syncthreads();

    const float mean = s_mean, inv = s_inv;
    float4* orow = out + ((size_t)b * CC + c) * T4;
    for (int i = tid; i < T4; i += 256) {
        float4 v = y[i];
        v.x = (v.x - mean) * inv;
        v.y = (v.y - mean) * inv;
        v.z = (v.z - mean) * inv;
        v.w = (v.w - mean) * inv;
        orow[i] = v;
    }
}

extern "C" void kernel_launch(void* const* d_in, const int* in_sizes, int n_in,
                              void* d_out, int out_size, void* d_ws, size_t ws_size,
                              hipStream_t stream) {
    const float4* x = (const float4*)d_in[0];
    float4* out = (float4*)d_out;
    float4* m = (float4*)d_ws;   // 64*10000 floats = 2.56 MB scratch

    dim3 g1((T4 + 255) / 256, BB);
    chmean_kernel<<<g1, 256, 0, stream>>>(x, m);

    zscore_kernel<<<BB * CC, 256, 0, stream>>>(x, m, out);
}